// Round 8
// baseline (225.773 us; speedup 1.0000x reference)
//
#include <hip/hip_runtime.h>
#include <math.h>

// B=4, S=4096, D=2048, E=64, K=2
#define NTOK    16384
#define DDIM    2048
#define NEXP    64
#define PSTRIDE (NTOK * NEXP)
#define ITERS   32                 // 32-k steps per wave (wave covers 1024 k)
#define SLICE_B 8192               // bytes per 32-k slice: [hi 64e x 4 chunks][lo ...]

#define AS1 __attribute__((address_space(1)))
#define AS3 __attribute__((address_space(3)))

typedef _Float16 half8   __attribute__((ext_vector_type(8)));
typedef float    floatx4 __attribute__((ext_vector_type(4)));

// ---------------------------------------------------------------------------
// W (fp32 [64][2048]) -> d_ws as 64 slices of 8 KB (one per 32-k chunk):
//   slice i32: [plane hi: e=0..63 x chunk c'=0..3 x 16B][plane lo: same]
// where chunk c' holds source k-chunk c = c' ^ ((e>>1)&3)  (bank swizzle so
// B-frag ds_read_b128 is <=2-way). lo = (w - hi) * 2^11.
// ---------------------------------------------------------------------------
__global__ __launch_bounds__(256) void wconv_kernel(
    const float* __restrict__ W, _Float16* __restrict__ ws)
{
    const int g     = blockIdx.x * 256 + threadIdx.x;   // 32768 16B-chunks
    const int i32   = g >> 9;                           // slice (32-k chunk)
    const int L     = g & 511;
    const int plane = L >> 8;
    const int r     = L & 255;
    const int e     = r >> 2;
    const int cp    = r & 3;
    const int c     = cp ^ ((e >> 1) & 3);
    const int k     = (i32 << 5) + (c << 3);

    const float* src = &W[(size_t)e * DDIM + k];
    floatx4 w0 = *(const floatx4*)src;
    floatx4 w1 = *(const floatx4*)(src + 4);

    half8 o;
#pragma unroll
    for (int i = 0; i < 4; ++i) {
        float f0 = w0[i], f1 = w1[i];
        _Float16 h0 = (_Float16)f0, h1 = (_Float16)f1;
        if (plane == 0) { o[i] = h0; o[4 + i] = h1; }
        else {
            o[i]     = (_Float16)((f0 - (float)h0) * 2048.0f);
            o[4 + i] = (_Float16)((f1 - (float)h1) * 2048.0f);
        }
    }
    *(half8*)((char*)ws + (size_t)g * 16) = o;
}

// ---------------------------------------------------------------------------
// Fused router, barrier-free K-loop with wave-private DMA staging.
// Block = 32 tokens, 4 waves (t = token-half, h = K-half). Grid 512
// (2 blocks/CU, 8 waves/CU). Each wave: 32 iters of 32 k; per iter it DMAs
// the NEXT slice into its private 2x8KB LDS ring (global_load_lds w16),
// prefetches x two iters ahead into regs, computes 12 MFMA from the current
// buffer. No __syncthreads in the loop -> loads stay in flight (fine-grained
// vmcnt). Two barriers at the end for the h-reduce; wave-local softmax+top2.
// ---------------------------------------------------------------------------
__global__ __launch_bounds__(256, 2) void router_kernel(
    const float* __restrict__ x,
    const _Float16* __restrict__ ws,
    const float* __restrict__ bias,
    float* __restrict__ out)
{
    __shared__ __align__(16) char wlds[4][2][SLICE_B];   // 64 KB: wave-private rings

    const int tid  = threadIdx.x;
    const int lane = tid & 63;
    const int wid  = tid >> 6;
    const int t    = wid >> 1;         // token half
    const int h    = wid & 1;          // K half (1024 each)
    const int t0   = blockIdx.x * 32 + t * 16;
    const int mrow = lane & 15;        // A token row / B expert col
    const int quad = lane >> 4;

    floatx4 acc_hh[4], acc_md[4];
#pragma unroll
    for (int j = 0; j < 4; ++j) { acc_hh[j] = (floatx4)0.0f; acc_md[j] = (floatx4)0.0f; }

    // x: row (t0+mrow), iter-i k = h*1024 + i*32 + quad*8
    const float* xrow = x + (size_t)(t0 + mrow) * DDIM + h * 1024 + quad * 8;
    // this wave's slice stream (32 slices of 8 KB starting at h*32)
    const char* wsrc = (const char*)ws + (size_t)h * 32 * SLICE_B + lane * 16;
    char* buf0 = &wlds[wid][0][0];
    char* buf1 = &wlds[wid][1][0];

    // precomputed per-j LDS offsets (halves): e*32 + (quad ^ ((e>>1)&3))*8
    int boff[4];
#pragma unroll
    for (int j = 0; j < 4; ++j) {
        const int e = j * 16 + mrow;
        boff[j] = e * 32 + ((quad ^ ((e >> 1) & 3)) << 3);
    }

#define DMA_SLICE(I, DST)                                                      \
    {                                                                          \
        const char* gs = wsrc + (size_t)(I) * SLICE_B;                         \
        _Pragma("unroll")                                                      \
        for (int q = 0; q < 8; ++q)                                            \
            __builtin_amdgcn_global_load_lds(                                  \
                (const AS1 unsigned int*)(const void*)(gs + q * 1024),         \
                (AS3 unsigned int*)(void*)((DST) + q * 1024), 16, 0, 0);       \
    }

    // ---- prologue: slice 0 DMA; x for iters 0 and 1 ----
    DMA_SLICE(0, buf0);
    floatx4 xa0 = *(const floatx4*)(xrow);
    floatx4 xa1 = *(const floatx4*)(xrow + 4);
    floatx4 xb0 = *(const floatx4*)(xrow + 32);
    floatx4 xb1 = *(const floatx4*)(xrow + 36);

#pragma unroll 2
    for (int i = 0; i < ITERS; ++i) {
        // issue next slice's DMA + x(i+2) FIRST (stay in flight over compute)
        if (i + 1 < ITERS) DMA_SLICE(i + 1, (i & 1) ? buf0 : buf1);
        floatx4 xn0, xn1;
        if (i + 2 < ITERS) {
            xn0 = *(const floatx4*)(xrow + (i + 2) * 32);
            xn1 = *(const floatx4*)(xrow + (i + 2) * 32 + 4);
        }

        // convert this iter's x to hi/lo fp16 fragments
        half8 a_hi, a_lo;
#pragma unroll
        for (int q = 0; q < 4; ++q) {
            float fv = xa0[q];
            _Float16 hh = (_Float16)fv;
            a_hi[q] = hh;
            a_lo[q] = (_Float16)((fv - (float)hh) * 2048.0f);
        }
#pragma unroll
        for (int q = 0; q < 4; ++q) {
            float fv = xa1[q];
            _Float16 hh = (_Float16)fv;
            a_hi[4 + q] = hh;
            a_lo[4 + q] = (_Float16)((fv - (float)hh) * 2048.0f);
        }

        // B from this wave's private buffer (own-vmcnt dependency only)
        const _Float16* lb = (const _Float16*)((i & 1) ? buf1 : buf0);
#pragma unroll
        for (int j = 0; j < 4; ++j) {
            half8 bh = *(const half8*)(lb + boff[j]);
            half8 bl = *(const half8*)(lb + 2048 + boff[j]);
            acc_hh[j] = __builtin_amdgcn_mfma_f32_16x16x32_f16(a_hi, bh, acc_hh[j], 0, 0, 0);
            acc_md[j] = __builtin_amdgcn_mfma_f32_16x16x32_f16(a_hi, bl, acc_md[j], 0, 0, 0);
            acc_md[j] = __builtin_amdgcn_mfma_f32_16x16x32_f16(a_lo, bh, acc_md[j], 0, 0, 0);
        }

        xa0 = xb0; xa1 = xb1; xb0 = xn0; xb1 = xn1;
    }

    // ---- combine planes; reduce h=1 -> h=0 through LDS ----
    float lg[4][4];
#pragma unroll
    for (int j = 0; j < 4; ++j)
#pragma unroll
        for (int r = 0; r < 4; ++r)
            lg[j][r] = acc_hh[j][r] + acc_md[j][r] * (1.0f / 2048.0f);

    __syncthreads();                      // all waves done with their rings
    float* rbuf = (float*)&wlds[0][0][0]; // 8 KB scratch, lane-major
    if (h == 1) {
#pragma unroll
        for (int j = 0; j < 4; ++j)
#pragma unroll
            for (int r = 0; r < 4; ++r)
                rbuf[t * 1024 + (j * 4 + r) * 64 + lane] = lg[j][r];
    }
    __syncthreads();
    if (h == 1) return;

#pragma unroll
    for (int j = 0; j < 4; ++j) {
        const float bj = bias[j * 16 + mrow];
#pragma unroll
        for (int r = 0; r < 4; ++r)
            lg[j][r] += rbuf[t * 1024 + (j * 4 + r) * 64 + lane] + bj;
    }

    // ---- epilogue: lane owns tokens t0 + quad*4 + r, experts j*16 + mrow ----
    const int c = mrow;
#pragma unroll
    for (int r = 0; r < 4; ++r) {
        const int trow = t0 + quad * 4 + r;

        float m = lg[0][r];
#pragma unroll
        for (int j = 1; j < 4; ++j) m = fmaxf(m, lg[j][r]);
#pragma unroll
        for (int off = 1; off <= 8; off <<= 1) m = fmaxf(m, __shfl_xor(m, off));

        float pj[4], s = 0.0f;
#pragma unroll
        for (int j = 0; j < 4; ++j) { pj[j] = __expf(lg[j][r] - m); s += pj[j]; }
#pragma unroll
        for (int off = 1; off <= 8; off <<= 1) s += __shfl_xor(s, off);
        const float rinv = 1.0f / s;

        // stable top-2 on logits (tie -> lower expert index)
        float v1 = -1e30f, v2 = -1e30f; int i1 = -1, i2 = -1;
#pragma unroll
        for (int j = 0; j < 4; ++j) {
            float v = lg[j][r]; int e = j * 16 + c;
            if (v > v1 || (v == v1 && e < i1)) { v2 = v1; i2 = i1; v1 = v; i1 = e; }
            else if (v > v2 || (v == v2 && e < i2)) { v2 = v; i2 = e; }
        }
#pragma unroll
        for (int off = 1; off <= 8; off <<= 1) {
            float u1 = __shfl_xor(v1, off); int q1 = __shfl_xor(i1, off);
            float u2 = __shfl_xor(v2, off); int q2 = __shfl_xor(i2, off);
            if (u1 > v1 || (u1 == v1 && q1 < i1)) {
                if (v1 > u2 || (v1 == u2 && i1 < q2)) { v2 = v1; i2 = i1; }
                else                                   { v2 = u2; i2 = q2; }
                v1 = u1; i1 = q1;
            } else {
                if (u1 > v2 || (u1 == v2 && q1 < i2)) { v2 = u1; i2 = q1; }
            }
        }

#pragma unroll
        for (int j = 0; j < 4; ++j) {
            const int col = j * 16 + c;
            const size_t o = (size_t)trow * NEXP + col;
            out[o]           = (col == i1 || col == i2) ? 1.0f : 0.0f;
            out[PSTRIDE + o] = pj[j] * rinv;
        }
    }
}

extern "C" void kernel_launch(void* const* d_in, const int* in_sizes, int n_in,
                              void* d_out, int out_size, void* d_ws, size_t ws_size,
                              hipStream_t stream) {
    const float* x = (const float*)d_in[0];   // [4,4096,2048] f32
    const float* W = (const float*)d_in[1];   // [64,2048] f32
    const float* b = (const float*)d_in[2];   // [64] f32
    (void)in_sizes; (void)n_in; (void)out_size; (void)ws_size;
    float* out = (float*)d_out;               // [masks | probs]

    _Float16* ws = (_Float16*)d_ws;           // 64 slices x 8 KB = 512 KB

    hipLaunchKernelGGL(wconv_kernel, dim3(128), dim3(256), 0, stream, W, ws);
    hipLaunchKernelGGL(router_kernel, dim3(NTOK / 32), dim3(256), 0, stream, x, ws, b, out);
}